// Round 12
// baseline (636.930 us; speedup 1.0000x reference)
//
#include <hip/hip_runtime.h>
#include <cstdint>
#include <cstddef>

#define D_MODEL 512
#define SEQ_T 2048
#define NHEADS 8
#define HDIM 64

typedef __attribute__((ext_vector_type(8))) short bf16x8;
typedef __attribute__((ext_vector_type(4))) float f32x4;

__device__ __forceinline__ unsigned short f2bf(float f) {
  unsigned int u = __float_as_uint(f);
  u += 0x7FFFu + ((u >> 16) & 1u);
  return (unsigned short)(u >> 16);
}

__device__ __forceinline__ unsigned int pack_bf16(float lo, float hi) {
  unsigned int a = __float_as_uint(lo) + 0x8000u;
  unsigned int b = __float_as_uint(hi) + 0x8000u;
  return __builtin_amdgcn_perm(b, a, 0x07060302u);
}

#define QSCALE 0.18033688011112043f
#define SSHIFT 16.0f
#define NBLK 768u

__device__ __forceinline__ void async_lds16(const unsigned short* g,
                                            unsigned short* l) {
  __builtin_amdgcn_global_load_lds(
      (const __attribute__((address_space(1))) void*)g,
      (__attribute__((address_space(3))) void*)l, 16, 0, 0);
}

// Software grid barrier: release-fence + device-scope arrive, acquire spin.
// Co-residency guaranteed (768 blocks, 3/CU by launch_bounds+LDS). Spin is
// capped so a violated assumption fails loudly instead of hanging.
__device__ __forceinline__ void gridbar(unsigned int* c) {
  __syncthreads();
  if (threadIdx.x == 0) {
    __threadfence();  // write-back dirty L2 (cross-XCD visibility)
    __hip_atomic_fetch_add(c, 1u, __ATOMIC_RELEASE, __HIP_MEMORY_SCOPE_AGENT);
    long guard = 0;
    while (__hip_atomic_load(c, __ATOMIC_ACQUIRE, __HIP_MEMORY_SCOPE_AGENT) <
           NBLK) {
      __builtin_amdgcn_s_sleep(2);
      if (++guard > (1L << 26)) break;  // fail loud, not hung
    }
    __threadfence();  // invalidate L1/L2 before consuming peer data
  }
  __syncthreads();
}

// ---------------------------------------------------------------------------
// r7's proven attention body for one (bh, qt) on shared buffers
// Ks[2][4096], Vs[2][4096], Pt[4][1024] (ushort).
// ---------------------------------------------------------------------------
__device__ void attn_one(const unsigned short* __restrict__ Qtb,
                         const unsigned short* __restrict__ Kb,
                         const unsigned short* __restrict__ Vtb,
                         unsigned short* __restrict__ AOb, int bh, int qt,
                         unsigned short* Ks, unsigned short* Vs,
                         unsigned short* Pt) {
  const int tid = threadIdx.x;
  const int w = tid >> 6, lane = tid & 63;
  const int quad = lane >> 4, l15 = lane & 15;

  const unsigned short* kbase = Kb + (size_t)bh * SEQ_T * HDIM;
  const unsigned short* vbase = Vtb + (size_t)bh * HDIM * SEQ_T;
  const int sr = tid >> 3;
  const int lc = tid & 7;
  const int scol = lc * 8;
  const int swc = (lc ^ (sr & 7)) * 8;

  bf16x8 qf0, qf1;
  {
    unsigned short qraw[16];
    const unsigned short* qp =
        Qtb + ((size_t)bh * HDIM + quad * 8) * SEQ_T + qt * 64 + w * 16 + l15;
#pragma unroll
    for (int jj = 0; jj < 8; ++jj) {
      qraw[jj] = qp[(size_t)jj * SEQ_T];
      qraw[8 + jj] = qp[(size_t)(32 + jj) * SEQ_T];
    }
    qf0 = *(const bf16x8*)qraw;
    qf1 = *(const bf16x8*)(qraw + 8);
  }
  const short oneb = (short)0x3F80;
  const bf16x8 ones = {oneb, oneb, oneb, oneb, oneb, oneb, oneb, oneb};

  f32x4 O[4] = {{0.f, 0.f, 0.f, 0.f}, {0.f, 0.f, 0.f, 0.f},
                {0.f, 0.f, 0.f, 0.f}, {0.f, 0.f, 0.f, 0.f}};
  f32x4 l_acc = {0.f, 0.f, 0.f, 0.f};
  const int q_rel = w * 16 + l15;
  const int r7 = l15 & 7;

  uint4 rk0, rk1, rv0, rv1;
  {
    const unsigned short* kp = kbase + (size_t)sr * 64 + scol;
    rk0 = *(const uint4*)kp;
    rk1 = *(const uint4*)(kp + 32 * 64);
    const unsigned short* vp = vbase + (size_t)sr * SEQ_T + scol;
    rv0 = *(const uint4*)vp;
    rv1 = *(const uint4*)(vp + 32 * SEQ_T);
  }
  *(uint4*)&Ks[sr * 64 + swc] = rk0;
  *(uint4*)&Ks[(sr + 32) * 64 + swc] = rk1;
  *(uint4*)&Vs[sr * 64 + swc] = rv0;
  *(uint4*)&Vs[(sr + 32) * 64 + swc] = rv1;
  __syncthreads();

  for (int i = 0; i < qt; ++i) {
    const int cur = i & 1;
    {
      const int nkt = i + 1;
      const unsigned short* kp = kbase + (size_t)(nkt * 64 + sr) * 64 + scol;
      rk0 = *(const uint4*)kp;
      rk1 = *(const uint4*)(kp + 32 * 64);
      const unsigned short* vp = vbase + (size_t)sr * SEQ_T + nkt * 64 + scol;
      rv0 = *(const uint4*)vp;
      rv1 = *(const uint4*)(vp + 32 * SEQ_T);
    }

    f32x4 S[4];
#pragma unroll
    for (int nb = 0; nb < 4; ++nb) {
      const int row = nb * 16 + l15;
      const unsigned short* k0p = &Ks[cur * 4096 + row * 64 + ((quad ^ r7) * 8)];
      const unsigned short* k1p =
          &Ks[cur * 4096 + row * 64 + (((quad + 4) ^ r7) * 8)];
      f32x4 z = {0.f, 0.f, 0.f, 0.f};
      z = __builtin_amdgcn_mfma_f32_16x16x32_bf16(*(const bf16x8*)k0p, qf0, z,
                                                  0, 0, 0);
      S[nb] = __builtin_amdgcn_mfma_f32_16x16x32_bf16(*(const bf16x8*)k1p, qf1,
                                                      z, 0, 0, 0);
    }

#pragma unroll
    for (int nb = 0; nb < 4; ++nb) {
      float p0 = __builtin_amdgcn_exp2f(S[nb][0] - SSHIFT);
      float p1 = __builtin_amdgcn_exp2f(S[nb][1] - SSHIFT);
      float p2 = __builtin_amdgcn_exp2f(S[nb][2] - SSHIFT);
      float p3 = __builtin_amdgcn_exp2f(S[nb][3] - SSHIFT);
      int cc = 2 * nb + (quad >> 1);
      uint2 pk = {pack_bf16(p0, p1), pack_bf16(p2, p3)};
      *(uint2*)&Pt[w * 1024 + l15 * 64 + ((cc ^ r7) * 8) + (quad & 1) * 4] = pk;
    }

    bf16x8 pb0 = *(const bf16x8*)&Pt[w * 1024 + l15 * 64 + ((quad ^ r7) * 8)];
    bf16x8 pb1 =
        *(const bf16x8*)&Pt[w * 1024 + l15 * 64 + (((quad + 4) ^ r7) * 8)];
    l_acc = __builtin_amdgcn_mfma_f32_16x16x32_bf16(ones, pb0, l_acc, 0, 0, 0);
    l_acc = __builtin_amdgcn_mfma_f32_16x16x32_bf16(ones, pb1, l_acc, 0, 0, 0);
#pragma unroll
    for (int nbd = 0; nbd < 4; ++nbd) {
      const int row = nbd * 16 + l15;
      const unsigned short* v0p = &Vs[cur * 4096 + row * 64 + ((quad ^ r7) * 8)];
      const unsigned short* v1p =
          &Vs[cur * 4096 + row * 64 + (((quad + 4) ^ r7) * 8)];
      O[nbd] = __builtin_amdgcn_mfma_f32_16x16x32_bf16(*(const bf16x8*)v0p, pb0,
                                                       O[nbd], 0, 0, 0);
      O[nbd] = __builtin_amdgcn_mfma_f32_16x16x32_bf16(*(const bf16x8*)v1p, pb1,
                                                       O[nbd], 0, 0, 0);
    }

    const int nxt = cur ^ 1;
    *(uint4*)&Ks[nxt * 4096 + sr * 64 + swc] = rk0;
    *(uint4*)&Ks[nxt * 4096 + (sr + 32) * 64 + swc] = rk1;
    *(uint4*)&Vs[nxt * 4096 + sr * 64 + swc] = rv0;
    *(uint4*)&Vs[nxt * 4096 + (sr + 32) * 64 + swc] = rv1;
    __syncthreads();
  }

  {  // diagonal tile
    const int cur = qt & 1;
    const int nb_lim = w + 1;
    f32x4 S[4];
#pragma unroll
    for (int nb = 0; nb < 4; ++nb) {
      if (nb < nb_lim) {
        const int row = nb * 16 + l15;
        const unsigned short* k0p =
            &Ks[cur * 4096 + row * 64 + ((quad ^ r7) * 8)];
        const unsigned short* k1p =
            &Ks[cur * 4096 + row * 64 + (((quad + 4) ^ r7) * 8)];
        f32x4 z = {0.f, 0.f, 0.f, 0.f};
        z = __builtin_amdgcn_mfma_f32_16x16x32_bf16(*(const bf16x8*)k0p, qf0,
                                                    z, 0, 0, 0);
        S[nb] = __builtin_amdgcn_mfma_f32_16x16x32_bf16(*(const bf16x8*)k1p,
                                                        qf1, z, 0, 0, 0);
      }
    }
#pragma unroll
    for (int nb = 0; nb < 4; ++nb) {
      int cc = 2 * nb + (quad >> 1);
      if (nb < nb_lim) {
        float pp[4];
#pragma unroll
        for (int r = 0; r < 4; ++r) {
          float p = __builtin_amdgcn_exp2f(S[nb][r] - SSHIFT);
          int key_rel = nb * 16 + quad * 4 + r;
          pp[r] = (key_rel > q_rel) ? 0.f : p;
        }
        uint2 pk = {pack_bf16(pp[0], pp[1]), pack_bf16(pp[2], pp[3])};
        *(uint2*)&Pt[w * 1024 + l15 * 64 + ((cc ^ r7) * 8) + (quad & 1) * 4] =
            pk;
      } else {
        uint2 z2 = {0u, 0u};
        *(uint2*)&Pt[w * 1024 + l15 * 64 + ((cc ^ r7) * 8) + (quad & 1) * 4] =
            z2;
      }
    }
    const int kpv = (w >= 2) ? 2 : 1;
    bf16x8 pb0 = *(const bf16x8*)&Pt[w * 1024 + l15 * 64 + ((quad ^ r7) * 8)];
    bf16x8 pb1 =
        *(const bf16x8*)&Pt[w * 1024 + l15 * 64 + (((quad + 4) ^ r7) * 8)];
    l_acc = __builtin_amdgcn_mfma_f32_16x16x32_bf16(ones, pb0, l_acc, 0, 0, 0);
    if (kpv == 2)
      l_acc =
          __builtin_amdgcn_mfma_f32_16x16x32_bf16(ones, pb1, l_acc, 0, 0, 0);
#pragma unroll
    for (int nbd = 0; nbd < 4; ++nbd) {
      const int row = nbd * 16 + l15;
      const unsigned short* v0p = &Vs[cur * 4096 + row * 64 + ((quad ^ r7) * 8)];
      O[nbd] = __builtin_amdgcn_mfma_f32_16x16x32_bf16(*(const bf16x8*)v0p, pb0,
                                                       O[nbd], 0, 0, 0);
      if (kpv == 2) {
        const unsigned short* v1p =
            &Vs[cur * 4096 + row * 64 + (((quad + 4) ^ r7) * 8)];
        O[nbd] = __builtin_amdgcn_mfma_f32_16x16x32_bf16(*(const bf16x8*)v1p,
                                                         pb1, O[nbd], 0, 0, 0);
      }
    }
  }

  float inv = 1.0f / l_acc[0];
  const int bb = bh >> 3, h = bh & 7;
  int qrow = qt * 64 + q_rel;
  unsigned short* dst = AOb + ((size_t)bb * SEQ_T + qrow) * D_MODEL + (h << 6);
#pragma unroll
  for (int nbd = 0; nbd < 4; ++nbd) {
    ushort4 o4 = {f2bf(O[nbd][0] * inv), f2bf(O[nbd][1] * inv),
                  f2bf(O[nbd][2] * inv), f2bf(O[nbd][3] * inv)};
    *(ushort4*)(dst + nbd * 16 + quad * 4) = o4;
  }
}

// ---------------------------------------------------------------------------
// Fused persistent kernel: prep -> qkv -> attention (work queue) -> out,
// separated by software grid barriers. 768 blocks, 3/CU guaranteed.
// ---------------------------------------------------------------------------
__global__ void __launch_bounds__(256, 3) fused_all(
    const float* __restrict__ x, const float* __restrict__ W_qkv,
    const float* __restrict__ b_qkv, const float* __restrict__ W_out,
    const float* __restrict__ b_out, float* __restrict__ out,
    unsigned short* __restrict__ xb, unsigned short* __restrict__ Wqkt,
    unsigned short* __restrict__ Wot, unsigned short* __restrict__ Qtb,
    unsigned short* __restrict__ Kb, unsigned short* __restrict__ Vtb,
    unsigned short* __restrict__ AOb, unsigned int* __restrict__ sync) {
  __shared__ __align__(16) unsigned char smem[40960];
  __shared__ int jshared;
  const int bid = blockIdx.x;
  const int tid = threadIdx.x;
  const int w = tid >> 6, lane = tid & 63;
  const int quad = lane >> 4, l15 = lane & 15;

  // ===== Phase 0: prep =====
  for (int ch = bid; ch < 2048; ch += 768) {
    int i = (ch * 256 + tid) * 8;
    float4 a = *(const float4*)(x + i);
    float4 b = *(const float4*)(x + i + 4);
    ushort4 lo = {f2bf(a.x), f2bf(a.y), f2bf(a.z), f2bf(a.w)};
    ushort4 hi = {f2bf(b.x), f2bf(b.y), f2bf(b.z), f2bf(b.w)};
    *(ushort4*)(xb + i) = lo;
    *(ushort4*)(xb + i + 4) = hi;
  }
  if (bid < 256) {
    float(*tile)[65] = (float(*)[65])smem;
    const float* src;
    unsigned short* dst;
    int C, c0, r0;
    if (bid < 192) {
      C = 1536; c0 = (bid % 24) * 64; r0 = (bid / 24) * 64;
      src = W_qkv; dst = Wqkt;
    } else {
      int t = bid - 192;
      C = 512; c0 = (t & 7) * 64; r0 = (t >> 3) * 64;
      src = W_out; dst = Wot;
    }
    for (int i = tid; i < 64 * 64; i += 256) {
      int r = i >> 6, c = i & 63;
      tile[r][c] = src[(size_t)(r0 + r) * C + c0 + c];
    }
    __syncthreads();
    for (int i = tid; i < 64 * 64; i += 256) {
      int c = i >> 6, r = i & 63;
      dst[(size_t)(c0 + c) * 512 + r0 + r] = f2bf(tile[r][c]);
    }
  }
  gridbar(&sync[0]);

  // ===== Phase 1: QKV GEMM, 768 tiles 1:1 =====
  {
    unsigned short* As = (unsigned short*)smem;
    unsigned short* Bs = As + 8192;
    const int wm = w >> 1, wn = w & 1;
    const int m0 = (bid & 63) * 128, n0 = (bid >> 6) * 128;

    const int srow = tid >> 3;
    const int schunk = (tid & 7) ^ (srow & 7);
    const unsigned short* ga = xb + (size_t)(m0 + srow) * 512 + schunk * 8;
    const unsigned short* gb = Wqkt + (size_t)(n0 + srow) * 512 + schunk * 8;
    unsigned short* lA = As + tid * 8;
    unsigned short* lB = Bs + tid * 8;

    f32x4 acc[4][4] = {};
    for (int k0 = 0; k0 < 512; k0 += 64) {
#pragma unroll
      for (int rr = 0; rr < 4; ++rr) {
        async_lds16(ga + (size_t)rr * 32 * 512 + k0, lA + rr * 2048);
        async_lds16(gb + (size_t)rr * 32 * 512 + k0, lB + rr * 2048);
      }
      __syncthreads();
      bf16x8 af[4][2], bfr[4][2];
#pragma unroll
      for (int mb = 0; mb < 4; ++mb) {
        int row = wm * 64 + mb * 16 + l15;
#pragma unroll
        for (int kk = 0; kk < 2; ++kk) {
          int slot = (kk * 4 + quad) ^ (row & 7);
          af[mb][kk] = *(const bf16x8*)&As[row * 64 + slot * 8];
        }
      }
#pragma unroll
      for (int nb = 0; nb < 4; ++nb) {
        int row = wn * 64 + nb * 16 + l15;
#pragma unroll
        for (int kk = 0; kk < 2; ++kk) {
          int slot = (kk * 4 + quad) ^ (row & 7);
          bfr[nb][kk] = *(const bf16x8*)&Bs[row * 64 + slot * 8];
        }
      }
#pragma unroll
      for (int mb = 0; mb < 4; ++mb)
#pragma unroll
        for (int nb = 0; nb < 4; ++nb) {
          acc[mb][nb] = __builtin_amdgcn_mfma_f32_16x16x32_bf16(
              af[mb][0], bfr[nb][0], acc[mb][nb], 0, 0, 0);
          acc[mb][nb] = __builtin_amdgcn_mfma_f32_16x16x32_bf16(
              af[mb][1], bfr[nb][1], acc[mb][nb], 0, 0, 0);
        }
      __syncthreads();
    }

    const int cbase = n0 + wn * 64;
    const int three = cbase >> 9;
    const int h = (cbase >> 6) & 7;
    const int bh = ((m0 >> 11) << 3) + h;
    const int t0 = (m0 & 2047) + wm * 64;
    float bv[4];
#pragma unroll
    for (int nb = 0; nb < 4; ++nb) bv[nb] = b_qkv[cbase + nb * 16 + l15];

    if (three == 0) {
#pragma unroll
      for (int mb = 0; mb < 4; ++mb)
#pragma unroll
        for (int nb = 0; nb < 4; ++nb) {
          int trow = t0 + mb * 16 + quad * 4;
          ushort4 v = {f2bf((acc[mb][nb][0] + bv[nb]) * QSCALE),
                       f2bf((acc[mb][nb][1] + bv[nb]) * QSCALE),
                       f2bf((acc[mb][nb][2] + bv[nb]) * QSCALE),
                       f2bf((acc[mb][nb][3] + bv[nb]) * QSCALE)};
          *(ushort4*)(Qtb + ((size_t)bh * HDIM + nb * 16 + l15) * SEQ_T +
                      trow) = v;
        }
    } else if (three == 2) {
#pragma unroll
      for (int mb = 0; mb < 4; ++mb)
#pragma unroll
        for (int nb = 0; nb < 4; ++nb) {
          int trow = t0 + mb * 16 + quad * 4;
          ushort4 v = {f2bf(acc[mb][nb][0] + bv[nb]),
                       f2bf(acc[mb][nb][1] + bv[nb]),
                       f2bf(acc[mb][nb][2] + bv[nb]),
                       f2bf(acc[mb][nb][3] + bv[nb])};
          *(ushort4*)(Vtb + ((size_t)bh * HDIM + nb * 16 + l15) * SEQ_T +
                      trow) = v;
        }
    } else {
#pragma unroll
      for (int mb = 0; mb < 4; ++mb)
#pragma unroll
        for (int nb = 0; nb < 4; ++nb)
#pragma unroll
          for (int r = 0; r < 4; ++r) {
            int trow = t0 + mb * 16 + quad * 4 + r;
            Kb[((size_t)bh * SEQ_T + trow) * HDIM + nb * 16 + l15] =
                f2bf(acc[mb][nb][r] + bv[nb]);
          }
    }
  }
  gridbar(&sync[1]);

  // ===== Phase 2: attention via global work queue (longest qt first) =====
  {
    unsigned short* Ks = (unsigned short*)smem;   // [2][4096]
    unsigned short* Vs = Ks + 8192;               // [2][4096]
    unsigned short* Pt = Vs + 8192;               // [4][1024]
    while (true) {
      if (tid == 0) jshared = (int)atomicAdd(&sync[3], 1u);
      __syncthreads();
      int jit = jshared;
      if (jit >= 1024) break;
      int qt = 31 - (jit >> 5);
      int bh = jit & 31;
      attn_one(Qtb, Kb, Vtb, AOb, bh, qt, Ks, Vs, Pt);
      __syncthreads();
    }
  }
  gridbar(&sync[2]);

  // ===== Phase 3: output projection on bid < 512 =====
  if (bid < 512) {
    unsigned short* As = (unsigned short*)smem;   // 64*64
    unsigned short* Bs = As + 4096;               // 128*64
    const int m0 = (bid & 127) * 64, n0 = (bid >> 7) * 128;

    const int srow = tid >> 3;
    const int schunk = (tid & 7) ^ (srow & 7);
    const unsigned short* ga = AOb + (size_t)(m0 + srow) * 512 + schunk * 8;
    const unsigned short* gb = Wot + (size_t)(n0 + srow) * 512 + schunk * 8;
    unsigned short* lA = As + tid * 8;
    unsigned short* lB = Bs + tid * 8;

    f32x4 acc[4][2] = {};
    for (int k0 = 0; k0 < 512; k0 += 64) {
#pragma unroll
      for (int rr = 0; rr < 2; ++rr)
        async_lds16(ga + (size_t)rr * 32 * 512 + k0, lA + rr * 2048);
#pragma unroll
      for (int rr = 0; rr < 4; ++rr)
        async_lds16(gb + (size_t)rr * 32 * 512 + k0, lB + rr * 2048);
      __syncthreads();
      bf16x8 af[4][2], bfr[2][2];
#pragma unroll
      for (int mb = 0; mb < 4; ++mb) {
        int row = mb * 16 + l15;
#pragma unroll
        for (int kk = 0; kk < 2; ++kk) {
          int slot = (kk * 4 + quad) ^ (row & 7);
          af[mb][kk] = *(const bf16x8*)&As[row * 64 + slot * 8];
        }
      }
#pragma unroll
      for (int nb = 0; nb < 2; ++nb) {
        int row = w * 32 + nb * 16 + l15;
#pragma unroll
        for (int kk = 0; kk < 2; ++kk) {
          int slot = (kk * 4 + quad) ^ (row & 7);
          bfr[nb][kk] = *(const bf16x8*)&Bs[row * 64 + slot * 8];
        }
      }
#pragma unroll
      for (int mb = 0; mb < 4; ++mb)
#pragma unroll
        for (int nb = 0; nb < 2; ++nb) {
          acc[mb][nb] = __builtin_amdgcn_mfma_f32_16x16x32_bf16(
              af[mb][0], bfr[nb][0], acc[mb][nb], 0, 0, 0);
          acc[mb][nb] = __builtin_amdgcn_mfma_f32_16x16x32_bf16(
              af[mb][1], bfr[nb][1], acc[mb][nb], 0, 0, 0);
        }
      __syncthreads();
    }

    const int cbase = n0 + w * 32;
    float bv[2];
#pragma unroll
    for (int nb = 0; nb < 2; ++nb) bv[nb] = b_out[cbase + nb * 16 + l15];
#pragma unroll
    for (int mb = 0; mb < 4; ++mb)
#pragma unroll
      for (int nb = 0; nb < 2; ++nb)
#pragma unroll
        for (int r = 0; r < 4; ++r)
          out[(size_t)(m0 + mb * 16 + quad * 4 + r) * 512 + cbase + nb * 16 +
              l15] = acc[mb][nb][r] + bv[nb];
  }
}

// ---------------------------------------------------------------------------
extern "C" void kernel_launch(void* const* d_in, const int* in_sizes, int n_in,
                              void* d_out, int out_size, void* d_ws,
                              size_t ws_size, hipStream_t stream) {
  const float* x     = (const float*)d_in[0];
  const float* W_qkv = (const float*)d_in[1];
  const float* b_qkv = (const float*)d_in[2];
  const float* W_out = (const float*)d_in[3];
  const float* b_out = (const float*)d_in[4];
  float* out = (float*)d_out;

  const size_t NX = (size_t)4 * SEQ_T * D_MODEL;        // 4,194,304
  unsigned short* xb   = (unsigned short*)d_ws;          // [8192][512]
  unsigned short* Wqkt = xb + NX;                        // [1536][512]
  unsigned short* Wot  = Wqkt + (size_t)1536 * 512;      // [512][512]
  unsigned short* Qtb  = Wot + (size_t)512 * 512;        // [bh][d][t]
  unsigned short* Kb   = Qtb + NX;                       // [bh][t][d]
  unsigned short* Vtb  = Kb + NX;                        // [bh][dv][t]
  unsigned short* AOb  = Vtb + NX;                       // [8192][512]
  unsigned int*  syncp = (unsigned int*)(AOb + NX);      // 4 counters

  hipMemsetAsync(syncp, 0, 4 * sizeof(unsigned int), stream);
  fused_all<<<dim3(768), dim3(256), 0, stream>>>(
      x, W_qkv, b_qkv, W_out, b_out, out, xb, Wqkt, Wot, Qtb, Kb, Vtb, AOb,
      syncp);
}